// Round 3
// baseline (452.990 us; speedup 1.0000x reference)
//
#include <hip/hip_runtime.h>
#include <hip/hip_bf16.h>

// Problem dims
#define T_TOK 4096
#define H_DIM 1024
#define I_DIM 1408
#define E_NUM 8
#define P_CAP 8192       // exactly 2*T pairs
#define G1_GRID 1136     // 8 XCD queues x 142 worst-case slots (gemm1)
#define G2_GRID 568      // 8 XCD queues x 71 slots (gemm2, exact)

typedef __bf16 bf16;
typedef __bf16 bf16x4 __attribute__((ext_vector_type(4)));
typedef __bf16 bf16x8 __attribute__((ext_vector_type(8)));
typedef float  f32x4  __attribute__((ext_vector_type(4)));

// async global->LDS, 16B per lane; LDS dest must be wave-uniform base (+lane*16 implicit)
// global source address is per-lane free -> we use it to bank-swizzle the LDS layout.
__device__ __forceinline__ void load_lds16(const void* g, void* l) {
  __builtin_amdgcn_global_load_lds((const __attribute__((address_space(1))) void*)g,
                                   (__attribute__((address_space(3))) void*)l, 16, 0, 0);
}

// ---------------- fused fp32 -> bf16 casts (x, wg, wu, wd) ----------------
__global__ __launch_bounds__(256) void cast_all(const float* __restrict__ x,
                                                const float* __restrict__ wg,
                                                const float* __restrict__ wu,
                                                const float* __restrict__ wd,
                                                bf16* __restrict__ xb, bf16* __restrict__ wgb,
                                                bf16* __restrict__ wub, bf16* __restrict__ wdb) {
  int b = blockIdx.x;
  const float* s; bf16* d; int base;
  if (b < 4096)       { s = x;  d = xb;  base = b; }
  else if (b < 15360) { s = wg; d = wgb; base = b - 4096; }
  else if (b < 26624) { s = wu; d = wub; base = b - 15360; }
  else                { s = wd; d = wdb; base = b - 26624; }
  size_t i = ((size_t)base * 256 + threadIdx.x) * 4;
  float4 v = *(const float4*)(s + i);
  bf16x4 o;
  o.x = (bf16)v.x; o.y = (bf16)v.y; o.z = (bf16)v.z; o.w = (bf16)v.w;
  *(bf16x4*)(d + i) = o;
}

// ---------------- router: fp32 logits (float4 loads), top-2, renorm weights ----------------
__global__ __launch_bounds__(256) void router_kernel(const float* __restrict__ x,
                                                     const float* __restrict__ rw,
                                                     int* __restrict__ tidx,
                                                     float* __restrict__ tw) {
  int t = blockIdx.x * 4 + (threadIdx.x >> 6);
  int lane = threadIdx.x & 63;
  const float4* xr  = (const float4*)(x + (size_t)t * H_DIM);
  const float4* rw4 = (const float4*)rw;
  float acc[E_NUM];
#pragma unroll
  for (int e = 0; e < E_NUM; ++e) acc[e] = 0.f;
  for (int c = lane; c < H_DIM / 4; c += 64) {   // 4 iters
    float4 xv = xr[c];
#pragma unroll
    for (int e = 0; e < E_NUM; ++e) {
      float4 rv = rw4[e * (H_DIM / 4) + c];
      acc[e] += xv.x * rv.x + xv.y * rv.y + xv.z * rv.z + xv.w * rv.w;
    }
  }
#pragma unroll
  for (int e = 0; e < E_NUM; ++e)
    for (int s = 32; s > 0; s >>= 1) acc[e] += __shfl_down(acc[e], s, 64);
  if (lane == 0) {
    int a = 0;
#pragma unroll
    for (int e = 1; e < E_NUM; ++e) if (acc[e] > acc[a]) a = e;
    int b = (a == 0) ? 1 : 0;
#pragma unroll
    for (int e = 0; e < E_NUM; ++e) if (e != a && acc[e] > acc[b]) b = e;
    float pb = expf(acc[b] - acc[a]);
    float inv = 1.f / (1.f + pb);
    tidx[t * 2] = a; tidx[t * 2 + 1] = b;
    tw[t * 2] = inv; tw[t * 2 + 1] = pb * inv;
  }
}

// ---------------- bucketize: ballot counts, XCD-aware block schedules, scatter ----------------
// sched pack: (e<<16) | (m<<8) | n0 ; -1 = dead block.
// gemm1: combo c = e*11+n0 -> XCD c%8. gemm2: combo c = e*8+n0 -> XCD n0 (c%8==n0).
__global__ __launch_bounds__(256) void bucket_kernel(const int* __restrict__ tidx,
                                                     int* __restrict__ pair_tok,
                                                     int* __restrict__ inv,
                                                     int* __restrict__ counts,
                                                     int* __restrict__ offsets,
                                                     int* __restrict__ sched1,
                                                     int* __restrict__ sched2) {
  __shared__ int sc[E_NUM], so[E_NUM], scur[E_NUM];
  int tid = threadIdx.x, lane = tid & 63, wv = tid >> 6;
  if (tid < E_NUM) sc[tid] = 0;
  for (int i = tid; i < G1_GRID; i += 256) sched1[i] = -1;
  for (int i = tid; i < G2_GRID; i += 256) sched2[i] = -1;
  __syncthreads();
  // counts via wave ballots
  int local[E_NUM];
#pragma unroll
  for (int e = 0; e < E_NUM; ++e) local[e] = 0;
  for (int base = wv * 64; base < P_CAP; base += 256) {
    int e = tidx[base + lane];
#pragma unroll
    for (int x = 0; x < E_NUM; ++x)
      local[x] += __popcll(__ballot(e == x));
  }
  if (lane == 0) {
#pragma unroll
    for (int x = 0; x < E_NUM; ++x) atomicAdd(&sc[x], local[x]);
  }
  __syncthreads();
  if (tid == 0) {
    int run = 0;
    for (int e = 0; e < E_NUM; ++e) { so[e] = run; run += sc[e]; }
    int q1[8] = {0,0,0,0,0,0,0,0};
    for (int c = 0; c < 88; ++c) {
      int e = c / 11, n0 = c % 11, k = c % 8;
      for (int m = 0; m * 128 < sc[e]; ++m) {
        sched1[q1[k] * 8 + k] = (e << 16) | (m << 8) | n0;
        ++q1[k];
      }
    }
    int q2[8] = {0,0,0,0,0,0,0,0};
    for (int c = 0; c < 64; ++c) {
      int e = c >> 3, n0 = c & 7, k = n0;
      for (int m = 0; m * 128 < sc[e]; ++m) {
        sched2[q2[k] * 8 + k] = (e << 16) | (m << 8) | n0;
        ++q2[k];
      }
    }
  }
  __syncthreads();
  if (tid < E_NUM) { scur[tid] = so[tid]; counts[tid] = sc[tid]; offsets[tid] = so[tid]; }
  __syncthreads();
  // scatter with wave-aggregated atomics; also build inverse map token->pair pos
  for (int base = wv * 64; base < P_CAP; base += 256) {
    int p = base + lane;
    int e = tidx[p];
#pragma unroll
    for (int x = 0; x < E_NUM; ++x) {
      bool mine = (e == x);
      unsigned long long m = __ballot(mine);
      if (m == 0) continue;  // wave-uniform
      int leader = __ffsll((long long)m) - 1;
      int n = __popcll(m);
      int bpos = 0;
      if (lane == leader) bpos = atomicAdd(&scur[x], n);
      bpos = __shfl(bpos, leader, 64);
      if (mine) {
        int rank = __popcll(m & ((1ull << lane) - 1ull));
        int pos = bpos + rank;
        pair_tok[pos] = p >> 1;
        inv[p] = pos;
      }
    }
  }
}

// ---------------- GEMM1: mid = silu(x@Wg^T) * (x@Wu^T), gathered rows ----------------
// 128x128 tile, BK=64, 4 waves (2x2), 16x16x32 bf16 MFMA, two accumulator sets.
// XOR bank swizzle on store (via global src addr), un-swizzle on fragment read.
__global__ __launch_bounds__(256, 2)
void gemm1_kernel(const bf16* __restrict__ xb, const bf16* __restrict__ wgb,
                  const bf16* __restrict__ wub, const int* __restrict__ pair_tok,
                  const int* __restrict__ counts, const int* __restrict__ offsets,
                  const int* __restrict__ sched1, bf16* __restrict__ mid) {
  const int sv = sched1[blockIdx.x];
  if (sv < 0) return;
  const int e  = sv >> 16;
  const int m0 = ((sv >> 8) & 0xff) << 7;
  const int n0 = (sv & 0xff) << 7;
  const int cnt = counts[e];
  const int off = offsets[e];

  __shared__ bf16 As[128 * 64];
  __shared__ bf16 Bgs[128 * 64];
  __shared__ bf16 Bus[128 * 64];

  const int tid = threadIdx.x;
  const int wave = tid >> 6;
  const int lane = tid & 63;
  const int wm = (wave >> 1) << 6;
  const int wn = (wave & 1) << 6;

  const bf16* wg_e = wgb + (size_t)e * (I_DIM * H_DIM);
  const bf16* wu_e = wub + (size_t)e * (I_DIM * H_DIM);

  int arow[4], acs[4], atok[4];
#pragma unroll
  for (int j = 0; j < 4; ++j) {
    int seg = ((wave << 2) + j) * 64 + lane;
    int row = seg >> 3;
    arow[j] = row;
    acs[j]  = ((seg & 7) ^ (row & 7)) << 3;      // swizzled col start (8 bf16 / 16B)
    int gr = m0 + row;
    int cr = gr < cnt ? gr : cnt - 1;
    atok[j] = pair_tok[off + cr];
  }

  f32x4 accg[4][4], accu[4][4];
#pragma unroll
  for (int i = 0; i < 4; ++i)
#pragma unroll
    for (int j = 0; j < 4; ++j) {
      accg[i][j] = (f32x4){0.f, 0.f, 0.f, 0.f};
      accu[i][j] = (f32x4){0.f, 0.f, 0.f, 0.f};
    }

  const int lr = lane & 15;
  const int sw = lr & 7;
  const int qd = lane >> 4;

  for (int k0 = 0; k0 < H_DIM; k0 += 64) {
#pragma unroll
    for (int j = 0; j < 4; ++j) {
      int base = ((wave << 2) + j) << 9;
      load_lds16(xb + (size_t)atok[j] * H_DIM + k0 + acs[j], As + base);
      load_lds16(wg_e + (size_t)(n0 + arow[j]) * H_DIM + k0 + acs[j], Bgs + base);
      load_lds16(wu_e + (size_t)(n0 + arow[j]) * H_DIM + k0 + acs[j], Bus + base);
    }
    __syncthreads();
#pragma unroll
    for (int ks = 0; ks < 2; ++ks) {
      const int kc = (((ks << 2) + qd) ^ sw) << 3;
      bf16x8 a[4], bg[4], bu[4];
#pragma unroll
      for (int i = 0; i < 4; ++i)
        a[i] = *(const bf16x8*)(As + (wm + (i << 4) + lr) * 64 + kc);
#pragma unroll
      for (int j = 0; j < 4; ++j) {
        bg[j] = *(const bf16x8*)(Bgs + (wn + (j << 4) + lr) * 64 + kc);
        bu[j] = *(const bf16x8*)(Bus + (wn + (j << 4) + lr) * 64 + kc);
      }
#pragma unroll
      for (int i = 0; i < 4; ++i)
#pragma unroll
        for (int j = 0; j < 4; ++j) {
          accg[i][j] = __builtin_amdgcn_mfma_f32_16x16x32_bf16(a[i], bg[j], accg[i][j], 0, 0, 0);
          accu[i][j] = __builtin_amdgcn_mfma_f32_16x16x32_bf16(a[i], bu[j], accu[i][j], 0, 0, 0);
        }
    }
    __syncthreads();
  }

#pragma unroll
  for (int i = 0; i < 4; ++i) {
#pragma unroll
    for (int r = 0; r < 4; ++r) {
      int row = wm + (i << 4) + (qd << 2) + r;  // C/D: row = quad*4+reg
      int gr = m0 + row;
      if (gr < cnt) {
        bf16* mrow = mid + (size_t)(off + gr) * I_DIM + n0 + wn;
#pragma unroll
        for (int j = 0; j < 4; ++j) {
          float g = accg[i][j][r], u = accu[i][j][r];
          float s = g / (1.f + __expf(-g));
          mrow[(j << 4) + lr] = (bf16)(s * u);  // C/D: col = lane&15
        }
      }
    }
  }
}

// ---------------- GEMM2: ybuf[p] = mid[p] @ Wd^T (raw, fp32, no atomics) ----------------
__global__ __launch_bounds__(256, 2)
void gemm2_kernel(const bf16* __restrict__ mid, const bf16* __restrict__ wdb,
                  const int* __restrict__ counts, const int* __restrict__ offsets,
                  const int* __restrict__ sched2, float* __restrict__ ybuf) {
  const int sv = sched2[blockIdx.x];
  if (sv < 0) return;
  const int e  = sv >> 16;
  const int m0 = ((sv >> 8) & 0xff) << 7;
  const int n0 = (sv & 0xff) << 7;
  const int cnt = counts[e];
  const int off = offsets[e];

  __shared__ bf16 As[128 * 64];
  __shared__ bf16 Bs[128 * 64];

  const int tid = threadIdx.x;
  const int wave = tid >> 6;
  const int lane = tid & 63;
  const int wm = (wave >> 1) << 6;
  const int wn = (wave & 1) << 6;

  const bf16* wd_e = wdb + (size_t)e * (H_DIM * I_DIM);

  int arow[4], acs[4];
  size_t apos[4];
#pragma unroll
  for (int j = 0; j < 4; ++j) {
    int seg = ((wave << 2) + j) * 64 + lane;
    int row = seg >> 3;
    arow[j] = row;
    acs[j]  = ((seg & 7) ^ (row & 7)) << 3;
    int gr = m0 + row;
    int cr = gr < cnt ? gr : cnt - 1;
    apos[j] = (size_t)(off + cr) * I_DIM + acs[j];
  }

  f32x4 acc[4][4];
#pragma unroll
  for (int i = 0; i < 4; ++i)
#pragma unroll
    for (int j = 0; j < 4; ++j) acc[i][j] = (f32x4){0.f, 0.f, 0.f, 0.f};

  const int lr = lane & 15;
  const int sw = lr & 7;
  const int qd = lane >> 4;

  for (int k0 = 0; k0 < I_DIM; k0 += 64) {  // 22 iters
#pragma unroll
    for (int j = 0; j < 4; ++j) {
      int base = ((wave << 2) + j) << 9;
      load_lds16(mid + apos[j] + k0, As + base);
      load_lds16(wd_e + (size_t)(n0 + arow[j]) * I_DIM + k0 + acs[j], Bs + base);
    }
    __syncthreads();
#pragma unroll
    for (int ks = 0; ks < 2; ++ks) {
      const int kc = (((ks << 2) + qd) ^ sw) << 3;
      bf16x8 a[4], b[4];
#pragma unroll
      for (int i = 0; i < 4; ++i)
        a[i] = *(const bf16x8*)(As + (wm + (i << 4) + lr) * 64 + kc);
#pragma unroll
      for (int j = 0; j < 4; ++j)
        b[j] = *(const bf16x8*)(Bs + (wn + (j << 4) + lr) * 64 + kc);
#pragma unroll
      for (int i = 0; i < 4; ++i)
#pragma unroll
        for (int j = 0; j < 4; ++j)
          acc[i][j] = __builtin_amdgcn_mfma_f32_16x16x32_bf16(a[i], b[j], acc[i][j], 0, 0, 0);
    }
    __syncthreads();
  }

#pragma unroll
  for (int i = 0; i < 4; ++i) {
#pragma unroll
    for (int r = 0; r < 4; ++r) {
      int row = wm + (i << 4) + (qd << 2) + r;
      int gr = m0 + row;
      if (gr < cnt) {
        float* yrow = ybuf + (size_t)(off + gr) * H_DIM + n0 + wn;
#pragma unroll
        for (int j = 0; j < 4; ++j)
          yrow[(j << 4) + lr] = acc[i][j][r];
      }
    }
  }
}

// ---------------- combine: out[t] = w0*y[p0] + w1*y[p1] ----------------
__global__ __launch_bounds__(256) void combine_kernel(const float* __restrict__ ybuf,
                                                      const int* __restrict__ inv,
                                                      const float* __restrict__ tw,
                                                      float* __restrict__ out) {
  int t = blockIdx.x;
  int p0 = inv[2 * t], p1 = inv[2 * t + 1];
  float w0 = tw[2 * t], w1 = tw[2 * t + 1];
  int h = threadIdx.x * 4;
  float4 a = *(const float4*)(ybuf + (size_t)p0 * H_DIM + h);
  float4 b = *(const float4*)(ybuf + (size_t)p1 * H_DIM + h);
  float4 o;
  o.x = w0 * a.x + w1 * b.x;
  o.y = w0 * a.y + w1 * b.y;
  o.z = w0 * a.z + w1 * b.z;
  o.w = w0 * a.w + w1 * b.w;
  *(float4*)(out + (size_t)t * H_DIM + h) = o;
}

extern "C" void kernel_launch(void* const* d_in, const int* in_sizes, int n_in,
                              void* d_out, int out_size, void* d_ws, size_t ws_size,
                              hipStream_t stream) {
  const float* x  = (const float*)d_in[0];   // [2,2048,1024]
  const float* rw = (const float*)d_in[1];   // [8,1024]
  const float* wg = (const float*)d_in[2];   // [8,1408,1024]
  const float* wu = (const float*)d_in[3];   // [8,1408,1024]
  const float* wd = (const float*)d_in[4];   // [8,1024,1408]
  float* out = (float*)d_out;

  char* ws = (char*)d_ws;
  bf16*  xb      = (bf16*)(ws);                    // 8,388,608 B
  bf16*  wgb     = (bf16*)(ws + 8388608);          // 23,068,672 B (dead after gemm1)
  bf16*  wub     = (bf16*)(ws + 31457280);         // 23,068,672 B (dead after gemm1)
  bf16*  wdb     = (bf16*)(ws + 54525952);         // 23,068,672 B
  bf16*  mid     = (bf16*)(ws + 77594624);         // 23,068,672 B
  float* ybuf    = (float*)(ws + 8388608);         // 33,554,432 B, overlays wgb+wub
  int*   tidx    = (int*)(ws + 100663296);         // 32,768 B
  float* tw      = (float*)(ws + 100696064);       // 32,768 B
  int*   ptok    = (int*)(ws + 100728832);         // 32,768 B
  int*   inv     = (int*)(ws + 100761600);         // 32,768 B
  int*   counts  = (int*)(ws + 100794368);         // 32 B
  int*   offsets = (int*)(ws + 100794400);         // 32 B
  int*   sched1  = (int*)(ws + 100794432);         // 4,544 B
  int*   sched2  = (int*)(ws + 100798976);         // 2,272 B

  cast_all<<<37888, 256, 0, stream>>>(x, wg, wu, wd, xb, wgb, wub, wdb);
  router_kernel<<<1024, 256, 0, stream>>>(x, rw, tidx, tw);
  bucket_kernel<<<1, 256, 0, stream>>>(tidx, ptok, inv, counts, offsets, sched1, sched2);
  gemm1_kernel<<<G1_GRID, 256, 0, stream>>>(xb, wgb, wub, ptok, counts, offsets, sched1, mid);
  gemm2_kernel<<<G2_GRID, 256, 0, stream>>>(mid, wdb, counts, offsets, sched2, ybuf);
  combine_kernel<<<T_TOK, 256, 0, stream>>>(ybuf, inv, tw, out);
}

// Round 4
// 320.251 us; speedup vs baseline: 1.4145x; 1.4145x over previous
//
#include <hip/hip_runtime.h>
#include <hip/hip_bf16.h>

// Problem dims
#define T_TOK 4096
#define H_DIM 1024
#define I_DIM 1408
#define E_NUM 8
#define P_CAP 8192       // exactly 2*T pairs
#define G1_SLOTS 142     // worst-case slots per XCD queue (gemm1)
#define G2_SLOTS 71      // slots per XCD queue (gemm2, exact)
#define G1_GRID (G1_SLOTS * 8)
#define G2_GRID (G2_SLOTS * 8)

typedef __bf16 bf16;
typedef __bf16 bf16x4 __attribute__((ext_vector_type(4)));
typedef __bf16 bf16x8 __attribute__((ext_vector_type(8)));
typedef float  f32x4  __attribute__((ext_vector_type(4)));

// async global->LDS, 16B per lane; LDS dest must be wave-uniform base (+lane*16 implicit)
// global source address is per-lane free -> we use it to bank-swizzle the LDS layout.
__device__ __forceinline__ void load_lds16(const void* g, void* l) {
  __builtin_amdgcn_global_load_lds((const __attribute__((address_space(1))) void*)g,
                                   (__attribute__((address_space(3))) void*)l, 16, 0, 0);
}

// ---------------- fused fp32 -> bf16 casts (x, wg, wu, wd) ----------------
__global__ __launch_bounds__(256) void cast_all(const float* __restrict__ x,
                                                const float* __restrict__ wg,
                                                const float* __restrict__ wu,
                                                const float* __restrict__ wd,
                                                bf16* __restrict__ xb, bf16* __restrict__ wgb,
                                                bf16* __restrict__ wub, bf16* __restrict__ wdb) {
  int b = blockIdx.x;
  const float* s; bf16* d; int base;
  if (b < 4096)       { s = x;  d = xb;  base = b; }
  else if (b < 15360) { s = wg; d = wgb; base = b - 4096; }
  else if (b < 26624) { s = wu; d = wub; base = b - 15360; }
  else                { s = wd; d = wdb; base = b - 26624; }
  size_t i = ((size_t)base * 256 + threadIdx.x) * 4;
  float4 v = *(const float4*)(s + i);
  bf16x4 o;
  o.x = (bf16)v.x; o.y = (bf16)v.y; o.z = (bf16)v.z; o.w = (bf16)v.w;
  *(bf16x4*)(d + i) = o;
}

// ---------------- router: fp32 logits (float4 loads), top-2, renorm weights ----------------
__global__ __launch_bounds__(256) void router_kernel(const float* __restrict__ x,
                                                     const float* __restrict__ rw,
                                                     int* __restrict__ tidx,
                                                     float* __restrict__ tw) {
  int t = blockIdx.x * 4 + (threadIdx.x >> 6);
  int lane = threadIdx.x & 63;
  const float4* xr  = (const float4*)(x + (size_t)t * H_DIM);
  const float4* rw4 = (const float4*)rw;
  float acc[E_NUM];
#pragma unroll
  for (int e = 0; e < E_NUM; ++e) acc[e] = 0.f;
  for (int c = lane; c < H_DIM / 4; c += 64) {   // 4 iters
    float4 xv = xr[c];
#pragma unroll
    for (int e = 0; e < E_NUM; ++e) {
      float4 rv = rw4[e * (H_DIM / 4) + c];
      acc[e] += xv.x * rv.x + xv.y * rv.y + xv.z * rv.z + xv.w * rv.w;
    }
  }
#pragma unroll
  for (int e = 0; e < E_NUM; ++e)
    for (int s = 32; s > 0; s >>= 1) acc[e] += __shfl_down(acc[e], s, 64);
  if (lane == 0) {
    int a = 0;
#pragma unroll
    for (int e = 1; e < E_NUM; ++e) if (acc[e] > acc[a]) a = e;
    int b = (a == 0) ? 1 : 0;
#pragma unroll
    for (int e = 0; e < E_NUM; ++e) if (e != a && acc[e] > acc[b]) b = e;
    float pb = expf(acc[b] - acc[a]);
    float inv = 1.f / (1.f + pb);
    tidx[t * 2] = a; tidx[t * 2 + 1] = b;
    tw[t * 2] = inv; tw[t * 2 + 1] = pb * inv;
  }
}

// ---------------- bucketize: ballot counts, atomic-free scatter, parallel scheds ----------------
// sched pack: (e<<16) | (m<<8) | n0 ; -1 = dead block.
// gemm1: combo c = e*11+n0 -> XCD queue c%8. gemm2: combo (e,n0) -> XCD queue n0.
// NOTE: no dynamically-indexed private arrays anywhere (they spill to scratch,
// ~900-cycle dependent chains -- that was the 169us round-3 regression).
__global__ __launch_bounds__(256) void bucket_kernel(const int* __restrict__ tidx,
                                                     int* __restrict__ pair_tok,
                                                     int* __restrict__ inv,
                                                     int* __restrict__ counts,
                                                     int* __restrict__ offsets,
                                                     int* __restrict__ sched1,
                                                     int* __restrict__ sched2) {
  __shared__ int sc[E_NUM], so[E_NUM];
  __shared__ int wcnt[4 * E_NUM];   // per-wave per-expert counts
  __shared__ int wbase[4 * E_NUM];  // per-wave per-expert scatter bases
  const int tid = threadIdx.x, lane = tid & 63, wv = tid >> 6;

  // Phase A: per-wave ballot counts (registers, unrolled indexing only)
  int lc0 = 0, lc1 = 0, lc2 = 0, lc3 = 0, lc4 = 0, lc5 = 0, lc6 = 0, lc7 = 0;
  for (int base = wv * 64; base < P_CAP; base += 256) {
    int e = tidx[base + lane];
    lc0 += __popcll(__ballot(e == 0)); lc1 += __popcll(__ballot(e == 1));
    lc2 += __popcll(__ballot(e == 2)); lc3 += __popcll(__ballot(e == 3));
    lc4 += __popcll(__ballot(e == 4)); lc5 += __popcll(__ballot(e == 5));
    lc6 += __popcll(__ballot(e == 6)); lc7 += __popcll(__ballot(e == 7));
  }
  if (lane == 0) {
    wcnt[wv * 8 + 0] = lc0; wcnt[wv * 8 + 1] = lc1; wcnt[wv * 8 + 2] = lc2;
    wcnt[wv * 8 + 3] = lc3; wcnt[wv * 8 + 4] = lc4; wcnt[wv * 8 + 5] = lc5;
    wcnt[wv * 8 + 6] = lc6; wcnt[wv * 8 + 7] = lc7;
  }
  __syncthreads();

  // Phase B: expert totals + offsets (tid 0, tiny), then per-wave bases (tid<32)
  if (tid == 0) {
    int run = 0;
    for (int e = 0; e < E_NUM; ++e) {
      int s = wcnt[e] + wcnt[8 + e] + wcnt[16 + e] + wcnt[24 + e];
      sc[e] = s; so[e] = run; run += s;
    }
  }
  __syncthreads();
  if (tid < 32) {
    int w = tid >> 3, e = tid & 7;
    int b = so[e];
    for (int ww = 0; ww < w; ++ww) b += wcnt[ww * 8 + e];
    wbase[tid] = b;
  }
  if (tid < E_NUM) { counts[tid] = sc[tid]; offsets[tid] = so[tid]; }
  __syncthreads();

  // Phase C: atomic-free scatter via ballot prefix + register running offsets
  int wb0 = wbase[wv * 8 + 0], wb1 = wbase[wv * 8 + 1], wb2 = wbase[wv * 8 + 2],
      wb3 = wbase[wv * 8 + 3], wb4 = wbase[wv * 8 + 4], wb5 = wbase[wv * 8 + 5],
      wb6 = wbase[wv * 8 + 6], wb7 = wbase[wv * 8 + 7];
  const unsigned long long lt = (1ull << lane) - 1ull;
  for (int base = wv * 64; base < P_CAP; base += 256) {
    int p = base + lane;
    int e = tidx[p];
    int pos = 0;
    unsigned long long m;
    m = __ballot(e == 0); if (e == 0) pos = wb0 + __popcll(m & lt); wb0 += __popcll(m);
    m = __ballot(e == 1); if (e == 1) pos = wb1 + __popcll(m & lt); wb1 += __popcll(m);
    m = __ballot(e == 2); if (e == 2) pos = wb2 + __popcll(m & lt); wb2 += __popcll(m);
    m = __ballot(e == 3); if (e == 3) pos = wb3 + __popcll(m & lt); wb3 += __popcll(m);
    m = __ballot(e == 4); if (e == 4) pos = wb4 + __popcll(m & lt); wb4 += __popcll(m);
    m = __ballot(e == 5); if (e == 5) pos = wb5 + __popcll(m & lt); wb5 += __popcll(m);
    m = __ballot(e == 6); if (e == 6) pos = wb6 + __popcll(m & lt); wb6 += __popcll(m);
    m = __ballot(e == 7); if (e == 7) pos = wb7 + __popcll(m & lt); wb7 += __popcll(m);
    pair_tok[pos] = p >> 1;
    inv[p] = pos;
  }

  // Phase D: XCD-aware schedules, one thread per queue (scalar q -> registers)
  if (tid < 8) {
    const int k = tid;
    int q = 0;
    for (int c = k; c < 88; c += 8) {          // gemm1 combos, queue = c % 8
      int e = c / 11, n0 = c % 11;
      int mb = (sc[e] + 127) >> 7;
      for (int m = 0; m < mb; ++m) { sched1[q * 8 + k] = (e << 16) | (m << 8) | n0; ++q; }
    }
    for (; q < G1_SLOTS; ++q) sched1[q * 8 + k] = -1;
    q = 0;
    for (int e = 0; e < E_NUM; ++e) {          // gemm2: queue = n0 = k
      int mb = (sc[e] + 127) >> 7;
      for (int m = 0; m < mb; ++m) { sched2[q * 8 + k] = (e << 16) | (m << 8) | k; ++q; }
    }
    for (; q < G2_SLOTS; ++q) sched2[q * 8 + k] = -1;
  }
}

// ---------------- GEMM1: mid = silu(x@Wg^T) * (x@Wu^T), gathered rows ----------------
// 128x128 tile, BK=64, 4 waves (2x2), 16x16x32 bf16 MFMA, two accumulator sets.
// XOR bank swizzle on store (via global src addr), un-swizzle on fragment read.
__global__ __launch_bounds__(256, 2)
void gemm1_kernel(const bf16* __restrict__ xb, const bf16* __restrict__ wgb,
                  const bf16* __restrict__ wub, const int* __restrict__ pair_tok,
                  const int* __restrict__ counts, const int* __restrict__ offsets,
                  const int* __restrict__ sched1, bf16* __restrict__ mid) {
  const int sv = sched1[blockIdx.x];
  if (sv < 0) return;
  const int e  = sv >> 16;
  const int m0 = ((sv >> 8) & 0xff) << 7;
  const int n0 = (sv & 0xff) << 7;
  const int cnt = counts[e];
  const int off = offsets[e];

  __shared__ bf16 As[128 * 64];
  __shared__ bf16 Bgs[128 * 64];
  __shared__ bf16 Bus[128 * 64];

  const int tid = threadIdx.x;
  const int wave = tid >> 6;
  const int lane = tid & 63;
  const int wm = (wave >> 1) << 6;
  const int wn = (wave & 1) << 6;

  const bf16* wg_e = wgb + (size_t)e * (I_DIM * H_DIM);
  const bf16* wu_e = wub + (size_t)e * (I_DIM * H_DIM);

  int arow[4], acs[4], atok[4];
#pragma unroll
  for (int j = 0; j < 4; ++j) {
    int seg = ((wave << 2) + j) * 64 + lane;
    int row = seg >> 3;
    arow[j] = row;
    acs[j]  = ((seg & 7) ^ (row & 7)) << 3;      // swizzled col start (8 bf16 / 16B)
    int gr = m0 + row;
    int cr = gr < cnt ? gr : cnt - 1;
    atok[j] = pair_tok[off + cr];
  }

  f32x4 accg[4][4], accu[4][4];
#pragma unroll
  for (int i = 0; i < 4; ++i)
#pragma unroll
    for (int j = 0; j < 4; ++j) {
      accg[i][j] = (f32x4){0.f, 0.f, 0.f, 0.f};
      accu[i][j] = (f32x4){0.f, 0.f, 0.f, 0.f};
    }

  const int lr = lane & 15;
  const int sw = lr & 7;
  const int qd = lane >> 4;

  for (int k0 = 0; k0 < H_DIM; k0 += 64) {
#pragma unroll
    for (int j = 0; j < 4; ++j) {
      int base = ((wave << 2) + j) << 9;
      load_lds16(xb + (size_t)atok[j] * H_DIM + k0 + acs[j], As + base);
      load_lds16(wg_e + (size_t)(n0 + arow[j]) * H_DIM + k0 + acs[j], Bgs + base);
      load_lds16(wu_e + (size_t)(n0 + arow[j]) * H_DIM + k0 + acs[j], Bus + base);
    }
    __syncthreads();
#pragma unroll
    for (int ks = 0; ks < 2; ++ks) {
      const int kc = (((ks << 2) + qd) ^ sw) << 3;
      bf16x8 a[4], bg[4], bu[4];
#pragma unroll
      for (int i = 0; i < 4; ++i)
        a[i] = *(const bf16x8*)(As + (wm + (i << 4) + lr) * 64 + kc);
#pragma unroll
      for (int j = 0; j < 4; ++j) {
        bg[j] = *(const bf16x8*)(Bgs + (wn + (j << 4) + lr) * 64 + kc);
        bu[j] = *(const bf16x8*)(Bus + (wn + (j << 4) + lr) * 64 + kc);
      }
#pragma unroll
      for (int i = 0; i < 4; ++i)
#pragma unroll
        for (int j = 0; j < 4; ++j) {
          accg[i][j] = __builtin_amdgcn_mfma_f32_16x16x32_bf16(a[i], bg[j], accg[i][j], 0, 0, 0);
          accu[i][j] = __builtin_amdgcn_mfma_f32_16x16x32_bf16(a[i], bu[j], accu[i][j], 0, 0, 0);
        }
    }
    __syncthreads();
  }

#pragma unroll
  for (int i = 0; i < 4; ++i) {
#pragma unroll
    for (int r = 0; r < 4; ++r) {
      int row = wm + (i << 4) + (qd << 2) + r;  // C/D: row = quad*4+reg
      int gr = m0 + row;
      if (gr < cnt) {
        bf16* mrow = mid + (size_t)(off + gr) * I_DIM + n0 + wn;
#pragma unroll
        for (int j = 0; j < 4; ++j) {
          float g = accg[i][j][r], u = accu[i][j][r];
          float s = g / (1.f + __expf(-g));
          mrow[(j << 4) + lr] = (bf16)(s * u);  // C/D: col = lane&15
        }
      }
    }
  }
}

// ---------------- GEMM2: ybuf[p] = mid[p] @ Wd^T (raw, fp32, no atomics) ----------------
__global__ __launch_bounds__(256, 2)
void gemm2_kernel(const bf16* __restrict__ mid, const bf16* __restrict__ wdb,
                  const int* __restrict__ counts, const int* __restrict__ offsets,
                  const int* __restrict__ sched2, float* __restrict__ ybuf) {
  const int sv = sched2[blockIdx.x];
  if (sv < 0) return;
  const int e  = sv >> 16;
  const int m0 = ((sv >> 8) & 0xff) << 7;
  const int n0 = (sv & 0xff) << 7;
  const int cnt = counts[e];
  const int off = offsets[e];

  __shared__ bf16 As[128 * 64];
  __shared__ bf16 Bs[128 * 64];

  const int tid = threadIdx.x;
  const int wave = tid >> 6;
  const int lane = tid & 63;
  const int wm = (wave >> 1) << 6;
  const int wn = (wave & 1) << 6;

  const bf16* wd_e = wdb + (size_t)e * (H_DIM * I_DIM);

  int arow[4], acs[4];
  size_t apos[4];
#pragma unroll
  for (int j = 0; j < 4; ++j) {
    int seg = ((wave << 2) + j) * 64 + lane;
    int row = seg >> 3;
    arow[j] = row;
    acs[j]  = ((seg & 7) ^ (row & 7)) << 3;
    int gr = m0 + row;
    int cr = gr < cnt ? gr : cnt - 1;
    apos[j] = (size_t)(off + cr) * I_DIM + acs[j];
  }

  f32x4 acc[4][4];
#pragma unroll
  for (int i = 0; i < 4; ++i)
#pragma unroll
    for (int j = 0; j < 4; ++j) acc[i][j] = (f32x4){0.f, 0.f, 0.f, 0.f};

  const int lr = lane & 15;
  const int sw = lr & 7;
  const int qd = lane >> 4;

  for (int k0 = 0; k0 < I_DIM; k0 += 64) {  // 22 iters
#pragma unroll
    for (int j = 0; j < 4; ++j) {
      int base = ((wave << 2) + j) << 9;
      load_lds16(mid + apos[j] + k0, As + base);
      load_lds16(wd_e + (size_t)(n0 + arow[j]) * I_DIM + k0 + acs[j], Bs + base);
    }
    __syncthreads();
#pragma unroll
    for (int ks = 0; ks < 2; ++ks) {
      const int kc = (((ks << 2) + qd) ^ sw) << 3;
      bf16x8 a[4], b[4];
#pragma unroll
      for (int i = 0; i < 4; ++i)
        a[i] = *(const bf16x8*)(As + (wm + (i << 4) + lr) * 64 + kc);
#pragma unroll
      for (int j = 0; j < 4; ++j)
        b[j] = *(const bf16x8*)(Bs + (wn + (j << 4) + lr) * 64 + kc);
#pragma unroll
      for (int i = 0; i < 4; ++i)
#pragma unroll
        for (int j = 0; j < 4; ++j)
          acc[i][j] = __builtin_amdgcn_mfma_f32_16x16x32_bf16(a[i], b[j], acc[i][j], 0, 0, 0);
    }
    __syncthreads();
  }

#pragma unroll
  for (int i = 0; i < 4; ++i) {
#pragma unroll
    for (int r = 0; r < 4; ++r) {
      int row = wm + (i << 4) + (qd << 2) + r;
      int gr = m0 + row;
      if (gr < cnt) {
        float* yrow = ybuf + (size_t)(off + gr) * H_DIM + n0 + wn;
#pragma unroll
        for (int j = 0; j < 4; ++j)
          yrow[(j << 4) + lr] = acc[i][j][r];
      }
    }
  }
}

// ---------------- combine: out[t] = w0*y[p0] + w1*y[p1] ----------------
__global__ __launch_bounds__(256) void combine_kernel(const float* __restrict__ ybuf,
                                                      const int* __restrict__ inv,
                                                      const float* __restrict__ tw,
                                                      float* __restrict__ out) {
  int t = blockIdx.x;
  int p0 = inv[2 * t], p1 = inv[2 * t + 1];
  float w0 = tw[2 * t], w1 = tw[2 * t + 1];
  int h = threadIdx.x * 4;
  float4 a = *(const float4*)(ybuf + (size_t)p0 * H_DIM + h);
  float4 b = *(const float4*)(ybuf + (size_t)p1 * H_DIM + h);
  float4 o;
  o.x = w0 * a.x + w1 * b.x;
  o.y = w0 * a.y + w1 * b.y;
  o.z = w0 * a.z + w1 * b.z;
  o.w = w0 * a.w + w1 * b.w;
  *(float4*)(out + (size_t)t * H_DIM + h) = o;
}

extern "C" void kernel_launch(void* const* d_in, const int* in_sizes, int n_in,
                              void* d_out, int out_size, void* d_ws, size_t ws_size,
                              hipStream_t stream) {
  const float* x  = (const float*)d_in[0];   // [2,2048,1024]
  const float* rw = (const float*)d_in[1];   // [8,1024]
  const float* wg = (const float*)d_in[2];   // [8,1408,1024]
  const float* wu = (const float*)d_in[3];   // [8,1408,1024]
  const float* wd = (const float*)d_in[4];   // [8,1024,1408]
  float* out = (float*)d_out;

  char* ws = (char*)d_ws;
  bf16*  xb      = (bf16*)(ws);                    // 8,388,608 B
  bf16*  wgb     = (bf16*)(ws + 8388608);          // 23,068,672 B (dead after gemm1)
  bf16*  wub     = (bf16*)(ws + 31457280);         // 23,068,672 B (dead after gemm1)
  bf16*  wdb     = (bf16*)(ws + 54525952);         // 23,068,672 B
  bf16*  mid     = (bf16*)(ws + 77594624);         // 23,068,672 B
  float* ybuf    = (float*)(ws + 8388608);         // 33,554,432 B, overlays wgb+wub
  int*   tidx    = (int*)(ws + 100663296);         // 32,768 B
  float* tw      = (float*)(ws + 100696064);       // 32,768 B
  int*   ptok    = (int*)(ws + 100728832);         // 32,768 B
  int*   inv     = (int*)(ws + 100761600);         // 32,768 B
  int*   counts  = (int*)(ws + 100794368);         // 32 B
  int*   offsets = (int*)(ws + 100794400);         // 32 B
  int*   sched1  = (int*)(ws + 100794432);         // 4,544 B
  int*   sched2  = (int*)(ws + 100799232);         // 2,272 B

  cast_all<<<37888, 256, 0, stream>>>(x, wg, wu, wd, xb, wgb, wub, wdb);
  router_kernel<<<1024, 256, 0, stream>>>(x, rw, tidx, tw);
  bucket_kernel<<<1, 256, 0, stream>>>(tidx, ptok, inv, counts, offsets, sched1, sched2);
  gemm1_kernel<<<G1_GRID, 256, 0, stream>>>(xb, wgb, wub, ptok, counts, offsets, sched1, mid);
  gemm2_kernel<<<G2_GRID, 256, 0, stream>>>(mid, wdb, counts, offsets, sched2, ybuf);
  combine_kernel<<<T_TOK, 256, 0, stream>>>(ybuf, inv, tw, out);
}